// Round 13
// baseline (4497.578 us; speedup 1.0000x reference)
//
#include <hip/hip_runtime.h>

// ---------------- problem constants ----------------
constexpr int B_ = 8, N_ = 8192, NPOINT_ = 2048, NSAMPLE_ = 32;
constexpr int M_ROWS = B_ * NPOINT_ * NSAMPLE_;   // 524288
constexpr int NGROUP = B_ * NPOINT_;              // 16384
// ws layout (bytes) — TOTAL 6.3 MB. Defensive vs small ws_size.
constexpr size_t OFF_NXF   = 0;                   // 49152 f32 (f32 mirror of new_xyz)
constexpr size_t OFF_IDX   = 196608;              // 524288 u16 -> ends 1245184
constexpr size_t OFF_WF    = 1245184;             // 16576 f32  -> ends 1311488
constexpr size_t OFF_GB    = 1311488;             // 512 f32    -> ends 1313536
constexpr size_t OFF_STATS = 1313536;             // 512 f32    -> ends 1315584
constexpr size_t OFF_NP    = 1315584;             // 512 f32    -> ends 1317632
constexpr size_t OFF_FLAG  = 1317632;             // 1 i32
constexpr size_t OFF_DONE  = 1317648;             // 1 i32 (16-aligned)
constexpr size_t OFF_MAXB  = 2097152;             // 16384*128 bf16 -> ends 6291456
// f32 SoA xyz mirror lives INSIDE the MAXB region (786432 B < 4 MB):
// written by conv_kernel, read only by ballq_kernel, then p3 overwrites MAXB.

__device__ __forceinline__ float bf2f(unsigned short u) {
  union { unsigned u; float f; } x; x.u = ((unsigned)u) << 16; return x.f;
}
__device__ __forceinline__ float lo16f(unsigned u) {
  union { unsigned u; float f; } x; x.u = u << 16; return x.f;
}
__device__ __forceinline__ float hi16f(unsigned u) {
  union { unsigned u; float f; } x; x.u = u & 0xffff0000u; return x.f;
}
__device__ __forceinline__ unsigned short f2bf(float f) {
  union { float f; unsigned u; } x; x.f = f;
  unsigned u = x.u + 0x7FFFu + ((x.u >> 16) & 1u);
  return (unsigned short)(u >> 16);
}
__device__ __forceinline__ int f2i(float f) {
  union { float f; int i; } x; x.f = f; return x.i;
}
__device__ __forceinline__ float i2f(int i) {
  union { int i; float f; } x; x.i = i; return x.f;
}
__device__ __forceinline__ void unpack8(uint4 u, float* x) {
  x[0] = bf2f((unsigned short)(u.x & 0xffffu)); x[1] = bf2f((unsigned short)(u.x >> 16));
  x[2] = bf2f((unsigned short)(u.y & 0xffffu)); x[3] = bf2f((unsigned short)(u.y >> 16));
  x[4] = bf2f((unsigned short)(u.z & 0xffffu)); x[5] = bf2f((unsigned short)(u.z >> 16));
  x[6] = bf2f((unsigned short)(u.w & 0xffffu)); x[7] = bf2f((unsigned short)(u.w >> 16));
}
// dual-dtype scalar load: element i of tensor p
__device__ __forceinline__ float ldf(const void* p, size_t i, bool bf) {
  return bf ? bf2f(((const unsigned short*)p)[i]) : ((const float*)p)[i];
}
__device__ __forceinline__ void stf(void* p, size_t i, bool bf, float v) {
  if (bf) ((unsigned short*)p)[i] = f2bf(v);
  else    ((float*)p)[i] = v;
}

// DPP max step: v = max(v, lane-permuted v). VALU-speed cross-lane (no LDS pipe).
template <int CTRL>
__device__ __forceinline__ float dpp_maxf(float v) {
  int n = __builtin_amdgcn_update_dpp(0, f2i(v), CTRL, 0xF, 0xF, true);
  return fmaxf(v, i2f(n));
}

// ---------------- dtype detector ----------------
extern "C" __global__ void detect_kernel(const unsigned short* __restrict__ xyz,
                                         int* __restrict__ flag) {
  if (threadIdx.x == 0 && blockIdx.x == 0) {
    int sane = 0;
    for (int k = 0; k < 32; ++k) {
      int e = (xyz[2 * k] >> 7) & 0xff;
      if (e >= 90 && e <= 140) ++sane;
    }
    *flag = (sane >= 24) ? 1 : 0;
  }
}

// ---------------- weight / param up-convert ----------------
extern "C" __global__ void prep_kernel(
    const void* W1, const void* W2, const void* W3,
    const void* g1, const void* b1, const void* g2, const void* b2,
    const void* g3, const void* b3,
    float* __restrict__ wf, float* __restrict__ gb, const int* __restrict__ flag) {
  const bool bf = (*flag != 0);
  int i = blockIdx.x * 256 + threadIdx.x;
  if (i < 4288)       wf[i] = ldf(W1, i, bf);
  else if (i < 8384)  wf[i] = ldf(W2, i - 4288, bf);
  else if (i < 16576) wf[i] = ldf(W3, i - 8384, bf);
  else if (i < 17088) {
    int k = i - 16576; float v;
    if (k < 64)       v = ldf(g1, k, bf);
    else if (k < 128) v = ldf(b1, k - 64, bf);
    else if (k < 192) v = ldf(g2, k - 128, bf);
    else if (k < 256) v = ldf(b2, k - 192, bf);
    else if (k < 384) v = ldf(g3, k - 256, bf);
    else              v = ldf(b3, k - 384, bf);
    gb[k] = v;
  }
}

// ---------------- xyz -> f32 SoA mirror (for coalesced ballq loads) --------
extern "C" __global__ void conv_kernel(const void* xyz, float* __restrict__ sxyz,
                                       const int* __restrict__ flag) {
  const bool bf = (*flag != 0);
  int i = blockIdx.x * 256 + threadIdx.x;      // 0 .. B_*N_-1
  if (i < B_ * N_) {
    sxyz[i]             = ldf(xyz, (size_t)i * 3 + 0, bf);
    sxyz[B_*N_ + i]     = ldf(xyz, (size_t)i * 3 + 1, bf);
    sxyz[2*B_*N_ + i]   = ldf(xyz, (size_t)i * 3 + 2, bf);
  }
}

// ---------------- furthest point sampling (v13, frozen) --------------------
// Ledger R2-R12: four reduce structures, +-25% op count, 2/4 waves/SIMD,
// barrier removal (probe: only ~12%), clock heater, addrspace fix — all leave
// fps at ~2450-2570us. Unattributable with available counters; declared at
// its floor for this structure. FROZEN as control.
template <bool BF>
__device__ __forceinline__ void fps_body(
    const void* xyz, void* out, float* __restrict__ nxf) {
#pragma clang fp contract(off)
  __shared__ float4 slots[32];                 // addrspace(3) guaranteed
  const int b = blockIdx.x;
  const int t = threadIdx.x;
  const int lane = t & 63, w = t >> 6;
  const size_t base = (size_t)b * N_ * 3;
  float px[8], py[8], pz[8], d[8];
  if (BF) {
    const uint4* xp = (const uint4*)((const unsigned short*)xyz + base) + t * 3;
    unsigned cc[12];
#pragma unroll
    for (int m = 0; m < 3; ++m) {
      uint4 u = xp[m];
      cc[4*m+0] = u.x; cc[4*m+1] = u.y; cc[4*m+2] = u.z; cc[4*m+3] = u.w;
    }
#pragma unroll
    for (int k = 0; k < 8; ++k) {              // unpack once; bitwise == bf2f
      if ((k & 1) == 0) {
        unsigned ra = cc[(3*k) >> 1], rb = cc[((3*k) >> 1) + 1];
        px[k] = lo16f(ra); py[k] = hi16f(ra); pz[k] = lo16f(rb);
      } else {
        unsigned ra = cc[(3*k - 1) >> 1], rb = cc[(3*k + 1) >> 1];
        px[k] = hi16f(ra); py[k] = lo16f(rb); pz[k] = hi16f(rb);
      }
    }
  } else {
#pragma unroll
    for (int k = 0; k < 8; ++k) {
      int i = t * 8 + k;
      px[k] = ((const float*)xyz)[base + i*3 + 0];
      py[k] = ((const float*)xyz)[base + i*3 + 1];
      pz[k] = ((const float*)xyz)[base + i*3 + 2];
    }
  }
#pragma unroll
  for (int k = 0; k < 8; ++k) d[k] = 1e10f;
  // register ring for selected centers: thread (j&1023) owns j, slot j>>10
  float s0x=0.f,s0y=0.f,s0z=0.f, s1x=0.f,s1y=0.f,s1z=0.f;
  // j = 0 picks point 0 — same-address broadcast load from global
  float p0, p1, p2;
  if (BF) {
    const unsigned short* xp16 = (const unsigned short*)xyz + base;
    p0 = bf2f(xp16[0]); p1 = bf2f(xp16[1]); p2 = bf2f(xp16[2]);
  } else {
    p0 = ((const float*)xyz)[base + 0];
    p1 = ((const float*)xyz)[base + 1];
    p2 = ((const float*)xyz)[base + 2];
  }
  if (t == 0) { s0x = p0; s0y = p1; s0z = p2; }
  for (int j = 1; j < NPOINT_; ++j) {
    float bv = -1.0f;
#pragma unroll
    for (int k = 0; k < 8; ++k) {              // value-only: v_min + v_max
      float dx = px[k] - p0, dy = py[k] - p1, dz = pz[k] - p2;
      float d2 = (dx*dx + dy*dy) + dz*dz;     // plain ops: match numpy bitwise
      float dn = fminf(d[k], d2);
      d[k] = dn;
      bv = fmaxf(bv, dn);
    }
    // ---- L1: wave max via DPP (VALU speed, no LDS pipe) ----
    float g = bv;
    g = dpp_maxf<0xB1>(g);                     // xor1 (quad_perm)
    g = dpp_maxf<0x4E>(g);                     // xor2 (quad_perm)
    g = dpp_maxf<0x141>(g);                    // xor4 (row_half_mirror)
    g = dpp_maxf<0x140>(g);                    // xor8 (row_mirror)
    g = dpp_maxf<0x142>(g);                    // row_bcast15
    g = dpp_maxf<0x143>(g);                    // row_bcast31 -> lane63 = full
    float wmax = i2f(__builtin_amdgcn_readlane(f2i(g), 63));
    unsigned long long hm = __ballot(bv == wmax);
    int sl = (int)__builtin_ctzll(hm);         // lowest lane == lowest pi
    const int pb = (j & 1) << 4;
    if (lane == sl) {                          // winner lane only (~1/16 waves)
      int bk = 0;
#pragma unroll
      for (int k = 7; k >= 1; --k)             // desc scan -> lowest matching k
        if (d[k] == bv) bk = k;
      float cx = px[0], cy = py[0], cz = pz[0];
#pragma unroll
      for (int k = 1; k < 8; ++k)
        if (bk == k) { cx = px[k]; cy = py[k]; cz = pz[k]; }
      slots[pb + w] = make_float4(bv, cx, cy, cz);
    }
    __syncthreads();                           // the ONLY barrier per iteration
    // ---- L2: cross-wave max via one b128 read + 4 DPP steps ----
    float4 kc = slots[pb + (lane & 15)];
    float m2 = kc.x;
    m2 = dpp_maxf<0xB1>(m2);
    m2 = dpp_maxf<0x4E>(m2);
    m2 = dpp_maxf<0x141>(m2);
    m2 = dpp_maxf<0x140>(m2);                  // 16-periodic -> all lanes = max
    unsigned long long bm = __ballot(kc.x == m2);
    int s2 = (int)__builtin_ctzll(bm);         // lowest wave = lowest pi range
    p0 = i2f(__builtin_amdgcn_readlane(f2i(kc.y), s2));
    p1 = i2f(__builtin_amdgcn_readlane(f2i(kc.z), s2));
    p2 = i2f(__builtin_amdgcn_readlane(f2i(kc.w), s2));
    if (t == (j & 1023)) {                     // bank center j (static slots)
      if ((j >> 10) == 0) { s0x = p0; s0y = p1; s0z = p2; }
      else                { s1x = p0; s1y = p1; s1z = p2; }
    }
  }
  // flush all 2048 selected centers (2 per thread, fully parallel)
  const bool bfrt = BF;
#pragma unroll
  for (int s = 0; s < 2; ++s) {
    float cx = (s==0)?s0x:s1x;
    float cy = (s==0)?s0y:s1y;
    float cz = (s==0)?s0z:s1z;
    size_t o = ((size_t)b * NPOINT_ + s * 1024 + t) * 3;
    nxf[o+0] = cx; nxf[o+1] = cy; nxf[o+2] = cz;
    stf(out, o+0, bfrt, cx); stf(out, o+1, bfrt, cy); stf(out, o+2, bfrt, cz);
  }
}

extern "C" __global__ void __launch_bounds__(1024, 4) fps_kernel(
    const void* xyz, void* out, float* __restrict__ nxf,
    const int* __restrict__ flag, int* __restrict__ done) {
  if (blockIdx.x < B_) {
    if (*flag != 0) fps_body<true>(xyz, out, nxf);
    else            fps_body<false>(xyz, out, nxf);
    __syncthreads();
    if (threadIdx.x == 0)
      __hip_atomic_fetch_add(done, 1, __ATOMIC_RELEASE, __HIP_MEMORY_SCOPE_AGENT);
  } else {
    // ---- heater: dummy FMA until all 8 real blocks report done ----
    float a = (float)threadIdx.x * 1e-9f + 1.0f;
    for (int o = 0; o < 20000; ++o) {          // bounded: guaranteed exit
#pragma unroll
      for (int k = 0; k < 256; ++k) a = fmaf(a, 1.0000001f, 1e-9f);
      asm volatile("" : "+v"(a));              // keep chain alive
      if (__hip_atomic_load(done, __ATOMIC_RELAXED, __HIP_MEMORY_SCOPE_AGENT) >= B_)
        break;
    }
  }
}

// ---------------- ball query: one wave per center (v2) ----------------
// Coalesced f32 SoA loads + rank-based PARALLEL emission (mbcnt) instead of
// the 32-deep serial lane-0 extraction loop. Emission order is ascending
// point index (rank = popcount of mask below lane) == reference's sorted
// order. d2 math bitwise identical (same f32 values via conv_kernel's ldf).
extern "C" __global__ void __launch_bounds__(256) ballq_kernel(
    const float* __restrict__ sxyz, const float* __restrict__ nxf,
    unsigned short* __restrict__ idxout) {
#pragma clang fp contract(off)
  const int gw = (int)((blockIdx.x * 256 + threadIdx.x) >> 6);
  const int lane = threadIdx.x & 63;
  const int b = gw >> 11;
  const int j = gw & (NPOINT_ - 1);
  const float* sx = sxyz;
  const float* sy = sxyz + B_ * N_;
  const float* sz = sxyz + 2 * B_ * N_;
  const size_t pbase = (size_t)b * N_;
  const size_t co = ((size_t)b * NPOINT_ + j) * 3;
  const float c0 = nxf[co], c1 = nxf[co+1], c2 = nxf[co+2];
  unsigned short* out = idxout + (size_t)gw * NSAMPLE_;
  int cnt = 0, first = -1;
  for (int c = 0; c < N_/64 && cnt < NSAMPLE_; ++c) {
    int i = c * 64 + lane;
    float dx = sx[pbase + i] - c0;
    float dy = sy[pbase + i] - c1;
    float dz = sz[pbase + i] - c2;
    float d2 = (dx*dx + dy*dy) + dz*dz;
    bool hit = d2 < 0.16f;
    unsigned long long m = __ballot(hit);
    if (m) {
      if (first < 0) first = c * 64 + (int)__builtin_ctzll(m);
      int rank = __builtin_amdgcn_mbcnt_hi(
          (unsigned)(m >> 32), __builtin_amdgcn_mbcnt_lo((unsigned)m, 0));
      if (hit) {
        int pos = cnt + rank;
        if (pos < NSAMPLE_) out[pos] = (unsigned short)i;
      }
      cnt += __builtin_popcountll(m);
    }
  }
  if (first < 0) first = 0;
  if (lane < NSAMPLE_ && lane >= cnt) out[lane] = (unsigned short)first;
}

// ---------------- shared row-compute building blocks ----------------
// Streams the 64-ch points row in 8-elem chunks (keeps x-liveness at 8 regs).
__device__ __forceinline__ void l1_row(
    const void* xyz, const void* points, const float* __restrict__ nxf,
    const unsigned short* __restrict__ idx, const float* __restrict__ wf,
    int r, bool bf, float* acc) {
  const int b = r >> 16;                       // 65536 rows per batch
  const int j = (r >> 5) & (NPOINT_ - 1);
  const int i = idx[r];
  const size_t pt = (size_t)b * N_ + i;
  const float* cp = nxf + ((size_t)b * NPOINT_ + j) * 3;
  float f0 = ldf(xyz, pt*3 + 0, bf) - cp[0];
  float f1 = ldf(xyz, pt*3 + 1, bf) - cp[1];
  float f2 = ldf(xyz, pt*3 + 2, bf) - cp[2];
#pragma unroll
  for (int c = 0; c < 64; ++c)
    acc[c] = fmaf(f0, wf[c], fmaf(f1, wf[64+c], f2 * wf[128+c]));
  const float* wp = wf + 192;
  if (bf) {
    const uint4* pp = (const uint4*)((const unsigned short*)points + pt * 64);
#pragma unroll
    for (int s = 0; s < 8; ++s) {
      uint4 u = pp[s];
      float x[8]; unpack8(u, x);
#pragma unroll
      for (int kk = 0; kk < 8; ++kk)
#pragma unroll
        for (int c = 0; c < 64; ++c)
          acc[c] = fmaf(x[kk], wp[(s*8+kk)*64 + c], acc[c]);
    }
  } else {
    const float4* pp = (const float4*)((const float*)points + pt * 64);
#pragma unroll
    for (int s = 0; s < 16; ++s) {
      float4 u = pp[s];
      float x[4] = {u.x, u.y, u.z, u.w};
#pragma unroll
      for (int kk = 0; kk < 4; ++kk)
#pragma unroll
        for (int c = 0; c < 64; ++c)
          acc[c] = fmaf(x[kk], wp[(s*4+kk)*64 + c], acc[c]);
    }
  }
}

template <int LDW>
__device__ __forceinline__ void mm64(const float* v, const float* __restrict__ w,
                                     float* acc) {
#pragma unroll
  for (int ch = 0; ch < 64; ++ch)
#pragma unroll
    for (int c = 0; c < 64; ++c)
      acc[c] = fmaf(v[ch], w[ch*LDW + c], acc[c]);
}

__device__ __forceinline__ void bnrelu64(float* v, const float* __restrict__ np0) {
#pragma unroll
  for (int c = 0; c < 64; ++c)
    v[c] = fmaxf(fmaf(v[c], np0[c], np0[64 + c]), 0.f);
}

// wave butterfly-sum of 64-elem array + its squares, LDS combine, block atomics
// (shfl_xor kept deliberately: ds_swizzle issues on the LDS pipe, which is
// SPARE capacity in these VALU-bound kernels — DPP would add to the VALU pipe)
__device__ __forceinline__ void commit_stats64(float* a, float* __restrict__ stats) {
  float q[64];
#pragma unroll
  for (int c = 0; c < 64; ++c) q[c] = a[c] * a[c];
#pragma unroll
  for (int off = 1; off < 64; off <<= 1)
#pragma unroll
    for (int c = 0; c < 64; ++c) {
      a[c] += __shfl_xor(a[c], off);
      q[c] += __shfl_xor(q[c], off);
    }
  __shared__ float LS[4][64], LQ[4][64];
  const int t = threadIdx.x, w = t >> 6;
  if ((t & 63) == 0) {
#pragma unroll
    for (int c = 0; c < 64; ++c) { LS[w][c] = a[c]; LQ[w][c] = q[c]; }
  }
  __syncthreads();
  if (t < 64) {
    atomicAdd(&stats[t],      LS[0][t] + LS[1][t] + LS[2][t] + LS[3][t]);
    atomicAdd(&stats[64 + t], LQ[0][t] + LQ[1][t] + LQ[2][t] + LQ[3][t]);
  }
}

// ---------------- pass 1: L1 row -> stats only ----------------
extern "C" __global__ void __launch_bounds__(256) p1_kernel(
    const void* xyz, const void* points, const float* __restrict__ nxf,
    const unsigned short* __restrict__ idx, const float* __restrict__ wf,
    float* __restrict__ stats, const int* __restrict__ flag) {
  const bool bf = (*flag != 0);
  const int r = blockIdx.x * 256 + threadIdx.x;
  float acc[64];
  l1_row(xyz, points, nxf, idx, wf, r, bf, acc);
  commit_stats64(acc, stats);
}

// ---------------- pass 2: L1 -> BN1 -> L2 -> stats ----------------
// R13: (256,1). R11 counters showed VGPR_Count=128 with v[64]+acc[64] = 128
// live floats -> ZERO temps -> spill/remat traffic (same allocator pathology
// as the R1 fps saga: the (256,2)=256 cap is ignored by the occupancy
// heuristic, which targets 128). min-waves=1 drops the heuristic target to
// 1 wave/SIMD so the allocator can use ~160-220 regs spill-free. ILP comes
// from 64 independent accumulation chains; weights arrive via scalar loads.
extern "C" __global__ void __launch_bounds__(256, 1) p2_kernel(
    const void* xyz, const void* points, const float* __restrict__ nxf,
    const unsigned short* __restrict__ idx, const float* __restrict__ wf,
    const float* __restrict__ w2, const float* __restrict__ np1,
    float* __restrict__ stats, const int* __restrict__ flag) {
  const bool bf = (*flag != 0);
  const int r = blockIdx.x * 256 + threadIdx.x;
  float v[64];
  l1_row(xyz, points, nxf, idx, wf, r, bf, v);
  bnrelu64(v, np1);
  float acc[64];
#pragma unroll
  for (int c = 0; c < 64; ++c) acc[c] = 0.f;
  mm64<64>(v, w2, acc);
  commit_stats64(acc, stats);
}

// ---------------- pass 3 (v2): one thread per ROW, no h-duplication --------
// R13: (256,1) — needs ~200 live floats (y2+y3+sc); see p2 comment.
extern "C" __global__ void __launch_bounds__(256, 1) p3_kernel(
    const void* xyz, const void* points, const float* __restrict__ nxf,
    const unsigned short* __restrict__ idx, const float* __restrict__ wf,
    const float* __restrict__ w2, const float* __restrict__ w3,
    const float* __restrict__ np1, const float* __restrict__ np2,
    unsigned short* __restrict__ maxb, float* __restrict__ stats,
    const int* __restrict__ flag) {
  const bool bf = (*flag != 0);
  const int t = threadIdx.x, lane = t & 63, w = t >> 6;
  const int r = blockIdx.x * 256 + t;
  const int g = r >> 5;
  float v[64];
  l1_row(xyz, points, nxf, idx, wf, r, bf, v);
  bnrelu64(v, np1);
  float y2[64];
#pragma unroll
  for (int c = 0; c < 64; ++c) y2[c] = 0.f;
  mm64<64>(v, w2, y2);
  bnrelu64(y2, np2);
  __shared__ float LSA[4][64], LQA[4][64], LSB[4][64], LQB[4][64];
  float* y3 = v;                               // reuse L1's dead registers
  float sc[64];
#pragma unroll
  for (int h = 0; h < 2; ++h) {
#pragma unroll
    for (int c = 0; c < 64; ++c) y3[c] = 0.f;
    mm64<128>(y2, w3 + h * 64, y3);
    // stats sumsq: sc = y3^2, butterfly over full wave
#pragma unroll
    for (int c = 0; c < 64; ++c) sc[c] = y3[c] * y3[c];
#pragma unroll
    for (int off = 1; off < 64; off <<= 1)
#pragma unroll
      for (int c = 0; c < 64; ++c) sc[c] += __shfl_xor(sc[c], off);
    if (lane == 0) {
#pragma unroll
      for (int c = 0; c < 64; ++c) {
        if (h == 0) LQA[w][c] = sc[c]; else LQB[w][c] = sc[c];
      }
    }
    // stats sum: sc = y3, butterfly
#pragma unroll
    for (int c = 0; c < 64; ++c) sc[c] = y3[c];
#pragma unroll
    for (int off = 1; off < 64; off <<= 1)
#pragma unroll
      for (int c = 0; c < 64; ++c) sc[c] += __shfl_xor(sc[c], off);
    if (lane == 0) {
#pragma unroll
      for (int c = 0; c < 64; ++c) {
        if (h == 0) LSA[w][c] = sc[c]; else LSB[w][c] = sc[c];
      }
    }
    // group max over the 32-lane half (raw y3), then write bf16 maxima
#pragma unroll
    for (int off = 1; off <= 16; off <<= 1)
#pragma unroll
      for (int c = 0; c < 64; ++c)
        y3[c] = fmaxf(y3[c], __shfl_xor(y3[c], off));
    if ((lane & 31) == 0) {
      unsigned short* mo = maxb + (size_t)g * 128 + h * 64;
#pragma unroll
      for (int c = 0; c < 64; ++c) mo[c] = f2bf(y3[c]);
    }
  }
  __syncthreads();
  if (t < 64) {
    atomicAdd(&stats[t],        LSA[0][t]+LSA[1][t]+LSA[2][t]+LSA[3][t]);
  } else if (t < 128) {
    int c = t - 64;
    atomicAdd(&stats[t],        LSB[0][c]+LSB[1][c]+LSB[2][c]+LSB[3][c]);
  } else if (t < 192) {
    int c = t - 128;
    atomicAdd(&stats[t],        LQA[0][c]+LQA[1][c]+LQA[2][c]+LQA[3][c]);
  } else {
    int c = t - 192;
    atomicAdd(&stats[t],        LQB[0][c]+LQB[1][c]+LQB[2][c]+LQB[3][c]);
  }
}

// ---------------- fold stats into (scale, shift) ----------------
extern "C" __global__ void nparam_kernel(
    const float* __restrict__ stats, const float* __restrict__ g,
    const float* __restrict__ bb, float* __restrict__ npar, int Cc) {
  int c = threadIdx.x;
  if (c < Cc) {
    float m = stats[c] * (1.0f / M_ROWS);
    float v = stats[Cc + c] * (1.0f / M_ROWS) - m * m;
    float sc = g[c] / sqrtf(v + 1e-5f);
    npar[c] = sc;
    npar[Cc + c] = bb[c] - m * sc;
  }
}

// ---------------- final: affine+relu on raw maxima -> out ----------------
extern "C" __global__ void __launch_bounds__(256) final_kernel(
    const unsigned short* __restrict__ maxb, const float* __restrict__ npar,
    void* out, const int* __restrict__ flag) {
  const bool bf = (*flag != 0);
  const int gtid = blockIdx.x * 256 + threadIdx.x;
  const int c = gtid & 127;
  float y = bf2f(maxb[gtid]);
  float r = fmaxf(fmaf(y, npar[c], npar[128 + c]), 0.f);
  stf(out, (size_t)B_ * NPOINT_ * 3 + gtid, bf, r);
}

extern "C" void kernel_launch(void* const* d_in, const int* in_sizes, int n_in,
                              void* d_out, int out_size, void* d_ws, size_t ws_size,
                              hipStream_t stream) {
  const void* xyz    = d_in[0];
  const void* points = d_in[1];
  char* ws = (char*)d_ws;
  float* nxf   = (float*)(ws + OFF_NXF);
  unsigned short* wsIdx = (unsigned short*)(ws + OFF_IDX);
  float* wf    = (float*)(ws + OFF_WF);
  float* gb    = (float*)(ws + OFF_GB);
  float* stats = (float*)(ws + OFF_STATS);
  float* npar  = (float*)(ws + OFF_NP);
  int*   flag  = (int*)(ws + OFF_FLAG);
  int*   done  = (int*)(ws + OFF_DONE);
  unsigned short* maxb = (unsigned short*)(ws + OFF_MAXB);
  float* sxyz  = (float*)(ws + OFF_MAXB);      // SoA mirror, reused before p3

  hipMemsetAsync(stats, 0, 512 * sizeof(float), stream);
  hipMemsetAsync(done, 0, sizeof(int), stream);
  detect_kernel<<<1, 64, 0, stream>>>((const unsigned short*)xyz, flag);
  prep_kernel<<<67, 256, 0, stream>>>(d_in[2], d_in[5], d_in[8], d_in[3], d_in[4],
                                      d_in[6], d_in[7], d_in[9], d_in[10], wf, gb, flag);
  conv_kernel<<<(B_ * N_) / 256, 256, 0, stream>>>(xyz, sxyz, flag);
  fps_kernel<<<128, 1024, 0, stream>>>(xyz, d_out, nxf, flag, done);
  ballq_kernel<<<(B_ * NPOINT_) / 4, 256, 0, stream>>>(sxyz, nxf, wsIdx);
  p1_kernel<<<M_ROWS / 256, 256, 0, stream>>>(xyz, points, nxf, wsIdx, wf, stats, flag);
  nparam_kernel<<<1, 128, 0, stream>>>(stats, gb, gb + 64, npar, 64);
  p2_kernel<<<M_ROWS / 256, 256, 0, stream>>>(xyz, points, nxf, wsIdx, wf, wf + 4288,
                                              npar, stats + 128, flag);
  nparam_kernel<<<1, 128, 0, stream>>>(stats + 128, gb + 128, gb + 192, npar + 128, 64);
  p3_kernel<<<M_ROWS / 256, 256, 0, stream>>>(xyz, points, nxf, wsIdx, wf,
                                              wf + 4288, wf + 8384, npar,
                                              npar + 128, maxb, stats + 256, flag);
  nparam_kernel<<<1, 128, 0, stream>>>(stats + 256, gb + 256, gb + 384, npar + 256, 128);
  final_kernel<<<(NGROUP * 128) / 256, 256, 0, stream>>>(maxb, npar + 256, d_out, flag);
}

// Round 16
// 3695.454 us; speedup vs baseline: 1.2171x; 1.2171x over previous
//
#include <hip/hip_runtime.h>

// ---------------- problem constants ----------------
constexpr int B_ = 8, N_ = 8192, NPOINT_ = 2048, NSAMPLE_ = 32;
constexpr int M_ROWS = B_ * NPOINT_ * NSAMPLE_;   // 524288
constexpr int NGROUP = B_ * NPOINT_;              // 16384
// ws layout (bytes) — TOTAL 6.3 MB. Defensive vs small ws_size.
constexpr size_t OFF_NXF   = 0;                   // 49152 f32 (f32 mirror of new_xyz)
constexpr size_t OFF_IDX   = 196608;              // 524288 u16 -> ends 1245184
constexpr size_t OFF_WF    = 1245184;             // 16576 f32  -> ends 1311488
constexpr size_t OFF_GB    = 1311488;             // 512 f32    -> ends 1313536
constexpr size_t OFF_STATS = 1313536;             // 512 f32    -> ends 1315584
constexpr size_t OFF_NP    = 1315584;             // 512 f32    -> ends 1317632
constexpr size_t OFF_FLAG  = 1317632;             // 1 i32
constexpr size_t OFF_DONE  = 1317648;             // 1 i32 (16-aligned)
constexpr size_t OFF_MAXB  = 2097152;             // 16384*128 bf16 -> ends 6291456
// f32 SoA xyz mirror lives INSIDE the MAXB region (786432 B < 4 MB):
// written by conv_kernel, read only by ballq_kernel, then p3 overwrites MAXB.

__device__ __forceinline__ float bf2f(unsigned short u) {
  union { unsigned u; float f; } x; x.u = ((unsigned)u) << 16; return x.f;
}
__device__ __forceinline__ float lo16f(unsigned u) {
  union { unsigned u; float f; } x; x.u = u << 16; return x.f;
}
__device__ __forceinline__ float hi16f(unsigned u) {
  union { unsigned u; float f; } x; x.u = u & 0xffff0000u; return x.f;
}
__device__ __forceinline__ unsigned short f2bf(float f) {
  union { float f; unsigned u; } x; x.f = f;
  unsigned u = x.u + 0x7FFFu + ((x.u >> 16) & 1u);
  return (unsigned short)(u >> 16);
}
__device__ __forceinline__ int f2i(float f) {
  union { float f; int i; } x; x.f = f; return x.i;
}
__device__ __forceinline__ float i2f(int i) {
  union { int i; float f; } x; x.i = i; return x.f;
}
__device__ __forceinline__ void unpack8(uint4 u, float* x) {
  x[0] = bf2f((unsigned short)(u.x & 0xffffu)); x[1] = bf2f((unsigned short)(u.x >> 16));
  x[2] = bf2f((unsigned short)(u.y & 0xffffu)); x[3] = bf2f((unsigned short)(u.y >> 16));
  x[4] = bf2f((unsigned short)(u.z & 0xffffu)); x[5] = bf2f((unsigned short)(u.z >> 16));
  x[6] = bf2f((unsigned short)(u.w & 0xffffu)); x[7] = bf2f((unsigned short)(u.w >> 16));
}
// dual-dtype scalar load: element i of tensor p
__device__ __forceinline__ float ldf(const void* p, size_t i, bool bf) {
  return bf ? bf2f(((const unsigned short*)p)[i]) : ((const float*)p)[i];
}
__device__ __forceinline__ void stf(void* p, size_t i, bool bf, float v) {
  if (bf) ((unsigned short*)p)[i] = f2bf(v);
  else    ((float*)p)[i] = v;
}

// DPP max step: v = max(v, lane-permuted v). VALU-speed cross-lane (no LDS pipe).
template <int CTRL>
__device__ __forceinline__ float dpp_maxf(float v) {
  int n = __builtin_amdgcn_update_dpp(0, f2i(v), CTRL, 0xF, 0xF, true);
  return fmaxf(v, i2f(n));
}

// ---- fold (recursive-halving) wave reduction, 64 lanes x 64 channels ------
// After the call, lane c holds sum over the 64 lanes of arr[c], in arr[0].
// Step s resolves channel bit (5-s) against lane bit (5-s): 63 shfl + 63 add
// + selects per array vs the replicated butterfly's 384+384. Tree shape
// differs from butterfly only in rounding order (stats flow through
// order-nondeterministic global atomics anyway).
__device__ __forceinline__ void fold64_sum2(float* a, float* q, int lane) {
#pragma unroll
  for (int s = 0; s < 6; ++s) {
    const int half = 32 >> s;                  // kept count & xor mask
    const bool hi = (lane & half) != 0;
#pragma unroll
    for (int i = 0; i < half; ++i) {
      float ka = hi ? a[i + half] : a[i];
      float sa = hi ? a[i]        : a[i + half];
      a[i] = ka + __shfl_xor(sa, half);
      float kq = hi ? q[i + half] : q[i];
      float sq = hi ? q[i]        : q[i + half];
      q[i] = kq + __shfl_xor(sq, half);
    }
  }
}

// ---------------- dtype detector ----------------
extern "C" __global__ void detect_kernel(const unsigned short* __restrict__ xyz,
                                         int* __restrict__ flag) {
  if (threadIdx.x == 0 && blockIdx.x == 0) {
    int sane = 0;
    for (int k = 0; k < 32; ++k) {
      int e = (xyz[2 * k] >> 7) & 0xff;
      if (e >= 90 && e <= 140) ++sane;
    }
    *flag = (sane >= 24) ? 1 : 0;
  }
}

// ---------------- weight / param up-convert ----------------
extern "C" __global__ void prep_kernel(
    const void* W1, const void* W2, const void* W3,
    const void* g1, const void* b1, const void* g2, const void* b2,
    const void* g3, const void* b3,
    float* __restrict__ wf, float* __restrict__ gb, const int* __restrict__ flag) {
  const bool bf = (*flag != 0);
  int i = blockIdx.x * 256 + threadIdx.x;
  if (i < 4288)       wf[i] = ldf(W1, i, bf);
  else if (i < 8384)  wf[i] = ldf(W2, i - 4288, bf);
  else if (i < 16576) wf[i] = ldf(W3, i - 8384, bf);
  else if (i < 17088) {
    int k = i - 16576; float v;
    if (k < 64)       v = ldf(g1, k, bf);
    else if (k < 128) v = ldf(b1, k - 64, bf);
    else if (k < 192) v = ldf(g2, k - 128, bf);
    else if (k < 256) v = ldf(b2, k - 192, bf);
    else if (k < 384) v = ldf(g3, k - 256, bf);
    else              v = ldf(b3, k - 384, bf);
    gb[k] = v;
  }
}

// ---------------- xyz -> f32 SoA mirror (for coalesced ballq loads) --------
extern "C" __global__ void conv_kernel(const void* xyz, float* __restrict__ sxyz,
                                       const int* __restrict__ flag) {
  const bool bf = (*flag != 0);
  int i = blockIdx.x * 256 + threadIdx.x;      // 0 .. B_*N_-1
  if (i < B_ * N_) {
    sxyz[i]             = ldf(xyz, (size_t)i * 3 + 0, bf);
    sxyz[B_*N_ + i]     = ldf(xyz, (size_t)i * 3 + 1, bf);
    sxyz[2*B_*N_ + i]   = ldf(xyz, (size_t)i * 3 + 2, bf);
  }
}

// ---------------- furthest point sampling (v13, frozen) --------------------
// Ledger R2-R12: four reduce structures, +-25% op count, 2/4 waves/SIMD,
// barrier removal (probe: only ~12%), clock heater, addrspace fix — all leave
// fps at ~2450-2570us. Unattributable with available counters; declared at
// its floor for this structure. FROZEN as control.
template <bool BF>
__device__ __forceinline__ void fps_body(
    const void* xyz, void* out, float* __restrict__ nxf) {
#pragma clang fp contract(off)
  __shared__ float4 slots[32];                 // addrspace(3) guaranteed
  const int b = blockIdx.x;
  const int t = threadIdx.x;
  const int lane = t & 63, w = t >> 6;
  const size_t base = (size_t)b * N_ * 3;
  float px[8], py[8], pz[8], d[8];
  if (BF) {
    const uint4* xp = (const uint4*)((const unsigned short*)xyz + base) + t * 3;
    unsigned cc[12];
#pragma unroll
    for (int m = 0; m < 3; ++m) {
      uint4 u = xp[m];
      cc[4*m+0] = u.x; cc[4*m+1] = u.y; cc[4*m+2] = u.z; cc[4*m+3] = u.w;
    }
#pragma unroll
    for (int k = 0; k < 8; ++k) {              // unpack once; bitwise == bf2f
      if ((k & 1) == 0) {
        unsigned ra = cc[(3*k) >> 1], rb = cc[((3*k) >> 1) + 1];
        px[k] = lo16f(ra); py[k] = hi16f(ra); pz[k] = lo16f(rb);
      } else {
        unsigned ra = cc[(3*k - 1) >> 1], rb = cc[(3*k + 1) >> 1];
        px[k] = hi16f(ra); py[k] = lo16f(rb); pz[k] = hi16f(rb);
      }
    }
  } else {
#pragma unroll
    for (int k = 0; k < 8; ++k) {
      int i = t * 8 + k;
      px[k] = ((const float*)xyz)[base + i*3 + 0];
      py[k] = ((const float*)xyz)[base + i*3 + 1];
      pz[k] = ((const float*)xyz)[base + i*3 + 2];
    }
  }
#pragma unroll
  for (int k = 0; k < 8; ++k) d[k] = 1e10f;
  // register ring for selected centers: thread (j&1023) owns j, slot j>>10
  float s0x=0.f,s0y=0.f,s0z=0.f, s1x=0.f,s1y=0.f,s1z=0.f;
  // j = 0 picks point 0 — same-address broadcast load from global
  float p0, p1, p2;
  if (BF) {
    const unsigned short* xp16 = (const unsigned short*)xyz + base;
    p0 = bf2f(xp16[0]); p1 = bf2f(xp16[1]); p2 = bf2f(xp16[2]);
  } else {
    p0 = ((const float*)xyz)[base + 0];
    p1 = ((const float*)xyz)[base + 1];
    p2 = ((const float*)xyz)[base + 2];
  }
  if (t == 0) { s0x = p0; s0y = p1; s0z = p2; }
  for (int j = 1; j < NPOINT_; ++j) {
    float bv = -1.0f;
#pragma unroll
    for (int k = 0; k < 8; ++k) {              // value-only: v_min + v_max
      float dx = px[k] - p0, dy = py[k] - p1, dz = pz[k] - p2;
      float d2 = (dx*dx + dy*dy) + dz*dz;     // plain ops: match numpy bitwise
      float dn = fminf(d[k], d2);
      d[k] = dn;
      bv = fmaxf(bv, dn);
    }
    // ---- L1: wave max via DPP (VALU speed, no LDS pipe) ----
    float g = bv;
    g = dpp_maxf<0xB1>(g);                     // xor1 (quad_perm)
    g = dpp_maxf<0x4E>(g);                     // xor2 (quad_perm)
    g = dpp_maxf<0x141>(g);                    // xor4 (row_half_mirror)
    g = dpp_maxf<0x140>(g);                    // xor8 (row_mirror)
    g = dpp_maxf<0x142>(g);                    // row_bcast15
    g = dpp_maxf<0x143>(g);                    // row_bcast31 -> lane63 = full
    float wmax = i2f(__builtin_amdgcn_readlane(f2i(g), 63));
    unsigned long long hm = __ballot(bv == wmax);
    int sl = (int)__builtin_ctzll(hm);         // lowest lane == lowest pi
    const int pb = (j & 1) << 4;
    if (lane == sl) {                          // winner lane only (~1/16 waves)
      int bk = 0;
#pragma unroll
      for (int k = 7; k >= 1; --k)             // desc scan -> lowest matching k
        if (d[k] == bv) bk = k;
      float cx = px[0], cy = py[0], cz = pz[0];
#pragma unroll
      for (int k = 1; k < 8; ++k)
        if (bk == k) { cx = px[k]; cy = py[k]; cz = pz[k]; }
      slots[pb + w] = make_float4(bv, cx, cy, cz);
    }
    __syncthreads();                           // the ONLY barrier per iteration
    // ---- L2: cross-wave max via one b128 read + 4 DPP steps ----
    float4 kc = slots[pb + (lane & 15)];
    float m2 = kc.x;
    m2 = dpp_maxf<0xB1>(m2);
    m2 = dpp_maxf<0x4E>(m2);
    m2 = dpp_maxf<0x141>(m2);
    m2 = dpp_maxf<0x140>(m2);                  // 16-periodic -> all lanes = max
    unsigned long long bm = __ballot(kc.x == m2);
    int s2 = (int)__builtin_ctzll(bm);         // lowest wave = lowest pi range
    p0 = i2f(__builtin_amdgcn_readlane(f2i(kc.y), s2));
    p1 = i2f(__builtin_amdgcn_readlane(f2i(kc.z), s2));
    p2 = i2f(__builtin_amdgcn_readlane(f2i(kc.w), s2));
    if (t == (j & 1023)) {                     // bank center j (static slots)
      if ((j >> 10) == 0) { s0x = p0; s0y = p1; s0z = p2; }
      else                { s1x = p0; s1y = p1; s1z = p2; }
    }
  }
  // flush all 2048 selected centers (2 per thread, fully parallel)
  const bool bfrt = BF;
#pragma unroll
  for (int s = 0; s < 2; ++s) {
    float cx = (s==0)?s0x:s1x;
    float cy = (s==0)?s0y:s1y;
    float cz = (s==0)?s0z:s1z;
    size_t o = ((size_t)b * NPOINT_ + s * 1024 + t) * 3;
    nxf[o+0] = cx; nxf[o+1] = cy; nxf[o+2] = cz;
    stf(out, o+0, bfrt, cx); stf(out, o+1, bfrt, cy); stf(out, o+2, bfrt, cz);
  }
}

extern "C" __global__ void __launch_bounds__(1024, 4) fps_kernel(
    const void* xyz, void* out, float* __restrict__ nxf,
    const int* __restrict__ flag, int* __restrict__ done) {
  if (blockIdx.x < B_) {
    if (*flag != 0) fps_body<true>(xyz, out, nxf);
    else            fps_body<false>(xyz, out, nxf);
    __syncthreads();
    if (threadIdx.x == 0)
      __hip_atomic_fetch_add(done, 1, __ATOMIC_RELEASE, __HIP_MEMORY_SCOPE_AGENT);
  } else {
    // ---- heater: dummy FMA until all 8 real blocks report done ----
    float a = (float)threadIdx.x * 1e-9f + 1.0f;
    for (int o = 0; o < 20000; ++o) {          // bounded: guaranteed exit
#pragma unroll
      for (int k = 0; k < 256; ++k) a = fmaf(a, 1.0000001f, 1e-9f);
      asm volatile("" : "+v"(a));              // keep chain alive
      if (__hip_atomic_load(done, __ATOMIC_RELAXED, __HIP_MEMORY_SCOPE_AGENT) >= B_)
        break;
    }
  }
}

// ---------------- ball query: one wave per center (v2) ----------------
// Coalesced f32 SoA loads + rank-based PARALLEL emission (mbcnt) instead of
// the 32-deep serial lane-0 extraction loop. Emission order is ascending
// point index (rank = popcount of mask below lane) == reference's sorted
// order. d2 math bitwise identical (same f32 values via conv_kernel's ldf).
extern "C" __global__ void __launch_bounds__(256) ballq_kernel(
    const float* __restrict__ sxyz, const float* __restrict__ nxf,
    unsigned short* __restrict__ idxout) {
#pragma clang fp contract(off)
  const int gw = (int)((blockIdx.x * 256 + threadIdx.x) >> 6);
  const int lane = threadIdx.x & 63;
  const int b = gw >> 11;
  const int j = gw & (NPOINT_ - 1);
  const float* sx = sxyz;
  const float* sy = sxyz + B_ * N_;
  const float* sz = sxyz + 2 * B_ * N_;
  const size_t pbase = (size_t)b * N_;
  const size_t co = ((size_t)b * NPOINT_ + j) * 3;
  const float c0 = nxf[co], c1 = nxf[co+1], c2 = nxf[co+2];
  unsigned short* out = idxout + (size_t)gw * NSAMPLE_;
  int cnt = 0, first = -1;
  for (int c = 0; c < N_/64 && cnt < NSAMPLE_; ++c) {
    int i = c * 64 + lane;
    float dx = sx[pbase + i] - c0;
    float dy = sy[pbase + i] - c1;
    float dz = sz[pbase + i] - c2;
    float d2 = (dx*dx + dy*dy) + dz*dz;
    bool hit = d2 < 0.16f;
    unsigned long long m = __ballot(hit);
    if (m) {
      if (first < 0) first = c * 64 + (int)__builtin_ctzll(m);
      int rank = __builtin_amdgcn_mbcnt_hi(
          (unsigned)(m >> 32), __builtin_amdgcn_mbcnt_lo((unsigned)m, 0));
      if (hit) {
        int pos = cnt + rank;
        if (pos < NSAMPLE_) out[pos] = (unsigned short)i;
      }
      cnt += __builtin_popcountll(m);
    }
  }
  if (first < 0) first = 0;
  if (lane < NSAMPLE_ && lane >= cnt) out[lane] = (unsigned short)first;
}

// ---------------- shared row-compute building blocks ----------------
// Streams the 64-ch points row in 8-elem chunks (keeps x-liveness at 8 regs).
__device__ __forceinline__ void l1_row(
    const void* xyz, const void* points, const float* __restrict__ nxf,
    const unsigned short* __restrict__ idx, const float* __restrict__ wf,
    int r, bool bf, float* acc) {
  const int b = r >> 16;                       // 65536 rows per batch
  const int j = (r >> 5) & (NPOINT_ - 1);
  const int i = idx[r];
  const size_t pt = (size_t)b * N_ + i;
  const float* cp = nxf + ((size_t)b * NPOINT_ + j) * 3;
  float f0 = ldf(xyz, pt*3 + 0, bf) - cp[0];
  float f1 = ldf(xyz, pt*3 + 1, bf) - cp[1];
  float f2 = ldf(xyz, pt*3 + 2, bf) - cp[2];
#pragma unroll
  for (int c = 0; c < 64; ++c)
    acc[c] = fmaf(f0, wf[c], fmaf(f1, wf[64+c], f2 * wf[128+c]));
  const float* wp = wf + 192;
  if (bf) {
    const uint4* pp = (const uint4*)((const unsigned short*)points + pt * 64);
#pragma unroll
    for (int s = 0; s < 8; ++s) {
      uint4 u = pp[s];
      float x[8]; unpack8(u, x);
#pragma unroll
      for (int kk = 0; kk < 8; ++kk)
#pragma unroll
        for (int c = 0; c < 64; ++c)
          acc[c] = fmaf(x[kk], wp[(s*8+kk)*64 + c], acc[c]);
    }
  } else {
    const float4* pp = (const float4*)((const float*)points + pt * 64);
#pragma unroll
    for (int s = 0; s < 16; ++s) {
      float4 u = pp[s];
      float x[4] = {u.x, u.y, u.z, u.w};
#pragma unroll
      for (int kk = 0; kk < 4; ++kk)
#pragma unroll
        for (int c = 0; c < 64; ++c)
          acc[c] = fmaf(x[kk], wp[(s*4+kk)*64 + c], acc[c]);
    }
  }
}

template <int LDW>
__device__ __forceinline__ void mm64(const float* v, const float* __restrict__ w,
                                     float* acc) {
#pragma unroll
  for (int ch = 0; ch < 64; ++ch)
#pragma unroll
    for (int c = 0; c < 64; ++c)
      acc[c] = fmaf(v[ch], w[ch*LDW + c], acc[c]);
}

__device__ __forceinline__ void bnrelu64(float* v, const float* __restrict__ np0) {
#pragma unroll
  for (int c = 0; c < 64; ++c)
    v[c] = fmaxf(fmaf(v[c], np0[c], np0[64 + c]), 0.f);
}

// wave FOLD-sum of 64-elem array + its squares, LDS combine, block atomics.
// R14: fold replaces the replicated butterfly (768+768 ops -> ~250+250).
// After fold, lane c owns channel c's wave sum; every lane stores 1 value.
__device__ __forceinline__ void commit_stats64(float* a, float* __restrict__ stats) {
  const int t = threadIdx.x, w = t >> 6, lane = t & 63;
  float q[64];
#pragma unroll
  for (int c = 0; c < 64; ++c) q[c] = a[c] * a[c];
  fold64_sum2(a, q, lane);
  __shared__ float LS[4][64], LQ[4][64];
  LS[w][lane] = a[0];
  LQ[w][lane] = q[0];
  __syncthreads();
  if (t < 64) {
    atomicAdd(&stats[t],      LS[0][t] + LS[1][t] + LS[2][t] + LS[3][t]);
    atomicAdd(&stats[64 + t], LQ[0][t] + LQ[1][t] + LQ[2][t] + LQ[3][t]);
  }
}

// ---------------- pass 1: L1 row -> stats only ----------------
extern "C" __global__ void __launch_bounds__(256) p1_kernel(
    const void* xyz, const void* points, const float* __restrict__ nxf,
    const unsigned short* __restrict__ idx, const float* __restrict__ wf,
    float* __restrict__ stats, const int* __restrict__ flag) {
  const bool bf = (*flag != 0);
  const int r = blockIdx.x * 256 + threadIdx.x;
  float acc[64];
  l1_row(xyz, points, nxf, idx, wf, r, bf, acc);
  commit_stats64(acc, stats);
}

// ---------------- pass 2: L1 -> BN1 -> L2 -> stats ----------------
// (256,2): R13 proved (256,1) costs ~650us (occupancy >> spill concerns).
extern "C" __global__ void __launch_bounds__(256, 2) p2_kernel(
    const void* xyz, const void* points, const float* __restrict__ nxf,
    const unsigned short* __restrict__ idx, const float* __restrict__ wf,
    const float* __restrict__ w2, const float* __restrict__ np1,
    float* __restrict__ stats, const int* __restrict__ flag) {
  const bool bf = (*flag != 0);
  const int r = blockIdx.x * 256 + threadIdx.x;
  float v[64];
  l1_row(xyz, points, nxf, idx, wf, r, bf, v);
  bnrelu64(v, np1);
  float acc[64];
#pragma unroll
  for (int c = 0; c < 64; ++c) acc[c] = 0.f;
  mm64<64>(v, w2, acc);
  commit_stats64(acc, stats);
}

// ---------------- pass 3 (v3): one thread per ROW + fold reductions --------
// One thread = one full row: L1 -> BN1 -> L2 -> BN2 -> per-half {L3, fold
// stats (sum+sq), fold group-max}. Fold group-max over the 32-lane half
// leaves lane hl owning channels 2hl, 2hl+1 -> every lane writes 2 u16.
// (256,2) restored per R13's occupancy lesson.
extern "C" __global__ void __launch_bounds__(256, 2) p3_kernel(
    const void* xyz, const void* points, const float* __restrict__ nxf,
    const unsigned short* __restrict__ idx, const float* __restrict__ wf,
    const float* __restrict__ w2, const float* __restrict__ w3,
    const float* __restrict__ np1, const float* __restrict__ np2,
    unsigned short* __restrict__ maxb, float* __restrict__ stats,
    const int* __restrict__ flag) {
  const bool bf = (*flag != 0);
  const int t = threadIdx.x, lane = t & 63, w = t >> 6;
  const int hl = lane & 31;
  const int r = blockIdx.x * 256 + t;
  const int g = r >> 5;
  float v[64];
  l1_row(xyz, points, nxf, idx, wf, r, bf, v);
  bnrelu64(v, np1);
  float y2[64];
#pragma unroll
  for (int c = 0; c < 64; ++c) y2[c] = 0.f;
  mm64<64>(v, w2, y2);
  bnrelu64(y2, np2);
  __shared__ float LSA[4][64], LQA[4][64], LSB[4][64], LQB[4][64];
  float* y3 = v;                               // reuse L1's dead registers
  float sc[64], sq[64];
#pragma unroll
  for (int h = 0; h < 2; ++h) {
#pragma unroll
    for (int c = 0; c < 64; ++c) y3[c] = 0.f;
    mm64<128>(y2, w3 + h * 64, y3);
    // stats: fold sum + sumsq over the full 64-lane wave
#pragma unroll
    for (int c = 0; c < 64; ++c) { sc[c] = y3[c]; sq[c] = y3[c] * y3[c]; }
    fold64_sum2(sc, sq, lane);
    if (h == 0) { LSA[w][lane] = sc[0]; LQA[w][lane] = sq[0]; }
    else        { LSB[w][lane] = sc[0]; LQB[w][lane] = sq[0]; }
    // group max: fold over the 32-lane half; lane hl ends with channels
    // 2hl (y3[0]) and 2hl+1 (y3[1]); every lane writes its 2 channels.
#pragma unroll
    for (int s = 0; s < 5; ++s) {
      const int half = 32 >> s;                // channel half: 32,16,8,4,2
      const int msk  = 16 >> s;                // lane xor within the 32-half
      const bool hi = (lane & msk) != 0;
#pragma unroll
      for (int i = 0; i < half; ++i) {
        float kv = hi ? y3[i + half] : y3[i];
        float sv = hi ? y3[i]        : y3[i + half];
        y3[i] = fmaxf(kv, __shfl_xor(sv, msk));
      }
    }
    unsigned short* mo = maxb + (size_t)g * 128 + h * 64;
    mo[2*hl + 0] = f2bf(y3[0]);
    mo[2*hl + 1] = f2bf(y3[1]);
  }
  __syncthreads();
  if (t < 64) {
    atomicAdd(&stats[t],        LSA[0][t]+LSA[1][t]+LSA[2][t]+LSA[3][t]);
  } else if (t < 128) {
    int c = t - 64;
    atomicAdd(&stats[t],        LSB[0][c]+LSB[1][c]+LSB[2][c]+LSB[3][c]);
  } else if (t < 192) {
    int c = t - 128;
    atomicAdd(&stats[t],        LQA[0][c]+LQA[1][c]+LQA[2][c]+LQA[3][c]);
  } else {
    int c = t - 192;
    atomicAdd(&stats[t],        LQB[0][c]+LQB[1][c]+LQB[2][c]+LQB[3][c]);
  }
}

// ---------------- fold stats into (scale, shift) ----------------
extern "C" __global__ void nparam_kernel(
    const float* __restrict__ stats, const float* __restrict__ g,
    const float* __restrict__ bb, float* __restrict__ npar, int Cc) {
  int c = threadIdx.x;
  if (c < Cc) {
    float m = stats[c] * (1.0f / M_ROWS);
    float v = stats[Cc + c] * (1.0f / M_ROWS) - m * m;
    float sc = g[c] / sqrtf(v + 1e-5f);
    npar[c] = sc;
    npar[Cc + c] = bb[c] - m * sc;
  }
}

// ---------------- final: affine+relu on raw maxima -> out ----------------
extern "C" __global__ void __launch_bounds__(256) final_kernel(
    const unsigned short* __restrict__ maxb, const float* __restrict__ npar,
    void* out, const int* __restrict__ flag) {
  const bool bf = (*flag != 0);
  const int gtid = blockIdx.x * 256 + threadIdx.x;
  const int c = gtid & 127;
  float y = bf2f(maxb[gtid]);
  float r = fmaxf(fmaf(y, npar[c], npar[128 + c]), 0.f);
  stf(out, (size_t)B_ * NPOINT_ * 3 + gtid, bf, r);
}

extern "C" void kernel_launch(void* const* d_in, const int* in_sizes, int n_in,
                              void* d_out, int out_size, void* d_ws, size_t ws_size,
                              hipStream_t stream) {
  const void* xyz    = d_in[0];
  const void* points = d_in[1];
  char* ws = (char*)d_ws;
  float* nxf   = (float*)(ws + OFF_NXF);
  unsigned short* wsIdx = (unsigned short*)(ws + OFF_IDX);
  float* wf    = (float*)(ws + OFF_WF);
  float* gb    = (float*)(ws + OFF_GB);
  float* stats = (float*)(ws + OFF_STATS);
  float* npar  = (float*)(ws + OFF_NP);
  int*   flag  = (int*)(ws + OFF_FLAG);
  int*   done  = (int*)(ws + OFF_DONE);
  unsigned short* maxb = (unsigned short*)(ws + OFF_MAXB);
  float* sxyz  = (float*)(ws + OFF_MAXB);      // SoA mirror, reused before p3

  hipMemsetAsync(stats, 0, 512 * sizeof(float), stream);
  hipMemsetAsync(done, 0, sizeof(int), stream);
  detect_kernel<<<1, 64, 0, stream>>>((const unsigned short*)xyz, flag);
  prep_kernel<<<67, 256, 0, stream>>>(d_in[2], d_in[5], d_in[8], d_in[3], d_in[4],
                                      d_in[6], d_in[7], d_in[9], d_in[10], wf, gb, flag);
  conv_kernel<<<(B_ * N_) / 256, 256, 0, stream>>>(xyz, sxyz, flag);
  fps_kernel<<<128, 1024, 0, stream>>>(xyz, d_out, nxf, flag, done);
  ballq_kernel<<<(B_ * NPOINT_) / 4, 256, 0, stream>>>(sxyz, nxf, wsIdx);
  p1_kernel<<<M_ROWS / 256, 256, 0, stream>>>(xyz, points, nxf, wsIdx, wf, stats, flag);
  nparam_kernel<<<1, 128, 0, stream>>>(stats, gb, gb + 64, npar, 64);
  p2_kernel<<<M_ROWS / 256, 256, 0, stream>>>(xyz, points, nxf, wsIdx, wf, wf + 4288,
                                              npar, stats + 128, flag);
  nparam_kernel<<<1, 128, 0, stream>>>(stats + 128, gb + 128, gb + 192, npar + 128, 64);
  p3_kernel<<<M_ROWS / 256, 256, 0, stream>>>(xyz, points, nxf, wsIdx, wf,
                                              wf + 4288, wf + 8384, npar,
                                              npar + 128, maxb, stats + 256, flag);
  nparam_kernel<<<1, 128, 0, stream>>>(stats + 256, gb + 256, gb + 384, npar + 256, 128);
  final_kernel<<<(NGROUP * 128) / 256, 256, 0, stream>>>(maxb, npar + 256, d_out, flag);
}